// Round 5
// baseline (1759.287 us; speedup 1.0000x reference)
//
#include <hip/hip_runtime.h>
#include <hip/hip_fp16.h>
#include <cstddef>

#define Wn 12
#define Nn 20000
#define Cn 64
#define En 320000
#define OFFS_STRIDE 20032

__device__ __forceinline__ float elu_f(float v) {
    return v > 0.f ? v : (expf(v) - 1.f);
}

// ---------------------------------------------------------------------------
// Weight transpose: [oc][ic][t] -> [oc][t][ic]  (sig block then gate block).
// ---------------------------------------------------------------------------
__global__ __launch_bounds__(256) void transw_kernel(
    const float* __restrict__ swv, const float* __restrict__ gwv,
    float* __restrict__ dst, int K)
{
    const int tot = 16 * 64 * K;
    for (int i = threadIdx.x + blockIdx.x * 256; i < 2 * tot; i += gridDim.x * 256) {
        const float* srcp = (i < tot) ? swv : gwv;
        int j  = (i < tot) ? i : i - tot;
        int oc = j / (64 * K);
        int r  = j - oc * 64 * K;     // t*64 + ic
        int t  = r >> 6;
        int ic = r & 63;
        dst[i] = srcp[(oc * 64 + ic) * K + t];
    }
}

// ---------------------------------------------------------------------------
// Inception gated temporal conv, K-group per BLOCK (blockIdx.y): all 4 waves
// in a block do identical work. Block = 16 nodes staged once into 62 KB LDS.
// ---------------------------------------------------------------------------
template<int K>
__device__ __forceinline__ void incep_v4(
    const float4* __restrict__ xq,
    const float4* __restrict__ swT,
    const float4* __restrict__ gwT,
    float* accs, float* accg)
{
    constexpr int P = (K - 1) / 2;
    for (int icb = 0; icb < 16; ++icb) {
        float4 xr[Wn];
        #pragma unroll
        for (int w = 0; w < Wn; ++w) xr[w] = xq[w * 20 + icb];
        #pragma unroll
        for (int t = 0; t < K; ++t) {
            const float4 wsv = swT[t * 16 + icb];
            const float4 wgv = gwT[t * 16 + icb];
            #pragma unroll
            for (int w = 0; w < Wn; ++w) {
                const int wp = w + t - P;
                if (wp >= 0 && wp < Wn) {
                    const float4 xv = xr[wp];
                    accs[w] = fmaf(xv.x, wsv.x, accs[w]);
                    accs[w] = fmaf(xv.y, wsv.y, accs[w]);
                    accs[w] = fmaf(xv.z, wsv.z, accs[w]);
                    accs[w] = fmaf(xv.w, wsv.w, accs[w]);
                    accg[w] = fmaf(xv.x, wgv.x, accg[w]);
                    accg[w] = fmaf(xv.y, wgv.y, accg[w]);
                    accg[w] = fmaf(xv.z, wgv.z, accg[w]);
                    accg[w] = fmaf(xv.w, wgv.w, accg[w]);
                }
            }
        }
    }
}

__global__ __launch_bounds__(256) void inception_kernel(
    const float* __restrict__ x,
    const float* __restrict__ sb1, const float* __restrict__ gb1,
    const float* __restrict__ sb3, const float* __restrict__ gb3,
    const float* __restrict__ sb5, const float* __restrict__ gb5,
    const float* __restrict__ sb7, const float* __restrict__ gb7,
    const float* __restrict__ wT,
    float* __restrict__ h)
{
    __shared__ float4 xs4[16 * 242];         // 61,952 B
    const int tid = threadIdx.x;
    const int nb  = blockIdx.x * 16;
    const int grp = blockIdx.y;              // K-group 0..3

    const float4* xg = (const float4*)x;
    for (int idx = tid; idx < 3072; idx += 256) {
        int nl  = idx / 192;
        int rem = idx - nl * 192;
        int w  = rem >> 4;
        int c4 = rem & 15;
        xs4[nl * 242 + w * 20 + c4] = xg[((size_t)w * Nn + nb + nl) * 16 + c4];
    }
    __syncthreads();

    const int lane = tid & 63;
    const int ocl  = lane & 15;
    const int node = (tid >> 6) * 4 + (lane >> 4);
    const float4* xq  = xs4 + node * 242;
    const float4* wT4 = (const float4*)wT;

    float bs, bg;
    switch (grp) {
      case 0:  bs = sb1[ocl]; bg = gb1[ocl]; break;
      case 1:  bs = sb3[ocl]; bg = gb3[ocl]; break;
      case 2:  bs = sb5[ocl]; bg = gb5[ocl]; break;
      default: bs = sb7[ocl]; bg = gb7[ocl]; break;
    }
    float accs[Wn], accg[Wn];
    #pragma unroll
    for (int w = 0; w < Wn; ++w) { accs[w] = bs; accg[w] = bg; }

    switch (grp) {
      case 0:  incep_v4<1>(xq, wT4 + 0    + ocl * 16,  wT4 + 256  + ocl * 16,  accs, accg); break;
      case 1:  incep_v4<3>(xq, wT4 + 512  + ocl * 48,  wT4 + 1280 + ocl * 48,  accs, accg); break;
      case 2:  incep_v4<5>(xq, wT4 + 2048 + ocl * 80,  wT4 + 3328 + ocl * 80,  accs, accg); break;
      default: incep_v4<7>(xq, wT4 + 4608 + ocl * 112, wT4 + 6400 + ocl * 112, accs, accg); break;
    }

    const int n  = nb + node;
    const int oc = grp * 16 + ocl;
    #pragma unroll
    for (int w = 0; w < Wn; ++w) {
        float s = accs[w];
        float g = accg[w];
        float r  = s > 0.f ? s : 0.f;
        float sg = 1.f / (1.f + expf(-g));
        h[((size_t)w * Nn + n) * Cn + oc] = r * sg;
    }
}

// ---------------------------------------------------------------------------
// Per-window (N x 64) @ (64 x 64) matmul, fp32 in -> fp16 out.
// 64 nodes/block, thread = 4x4 outer-product tile.
// GRID IS (Nn+63)/64: tail block clamps reads, guards stores.
// (Round-4 bug: Nn/64 truncated -> last 32 nodes of every window had
//  garbage t -> absmax 1.03.)
// ---------------------------------------------------------------------------
__global__ __launch_bounds__(256) void matmul_half_kernel(
    const float* __restrict__ h, const float* __restrict__ gw,
    __half* __restrict__ t)
{
    const int w  = blockIdx.y;
    const int nb = blockIdx.x * 64;
    __shared__ float wm[64 * 64];
    __shared__ float hT[64 * 64];
    const int tid = threadIdx.x;

    const float4* wsrc = (const float4*)(gw + (size_t)w * 4096);
    float4* wm4 = (float4*)wm;
    for (int i = tid; i < 1024; i += 256) wm4[i] = wsrc[i];

    {
        const int n = tid >> 2, icq = tid & 3;
        const int nclamp = (nb + n < Nn) ? (nb + n) : (Nn - 1);
        const float4* hsrc = (const float4*)(h + ((size_t)w * Nn + nclamp) * 64);
        #pragma unroll
        for (int k = 0; k < 4; ++k) {
            float4 v = hsrc[icq + 4 * k];
            int ic = (icq + 4 * k) * 4;
            hT[(ic + 0) * 64 + n] = v.x;
            hT[(ic + 1) * 64 + n] = v.y;
            hT[(ic + 2) * 64 + n] = v.z;
            hT[(ic + 3) * 64 + n] = v.w;
        }
    }
    __syncthreads();

    const int oc0 = (tid & 15) * 4;
    const int n0  = (tid >> 4) * 4;
    float acc[4][4] = {{0.f}};
    #pragma unroll
    for (int ic = 0; ic < 64; ++ic) {
        const float4 hv = *(const float4*)&hT[ic * 64 + n0];
        const float4 wv = *(const float4*)&wm[ic * 64 + oc0];
        acc[0][0] = fmaf(hv.x, wv.x, acc[0][0]);
        acc[0][1] = fmaf(hv.x, wv.y, acc[0][1]);
        acc[0][2] = fmaf(hv.x, wv.z, acc[0][2]);
        acc[0][3] = fmaf(hv.x, wv.w, acc[0][3]);
        acc[1][0] = fmaf(hv.y, wv.x, acc[1][0]);
        acc[1][1] = fmaf(hv.y, wv.y, acc[1][1]);
        acc[1][2] = fmaf(hv.y, wv.z, acc[1][2]);
        acc[1][3] = fmaf(hv.y, wv.w, acc[1][3]);
        acc[2][0] = fmaf(hv.z, wv.x, acc[2][0]);
        acc[2][1] = fmaf(hv.z, wv.y, acc[2][1]);
        acc[2][2] = fmaf(hv.z, wv.z, acc[2][2]);
        acc[2][3] = fmaf(hv.z, wv.w, acc[2][3]);
        acc[3][0] = fmaf(hv.w, wv.x, acc[3][0]);
        acc[3][1] = fmaf(hv.w, wv.y, acc[3][1]);
        acc[3][2] = fmaf(hv.w, wv.z, acc[3][2]);
        acc[3][3] = fmaf(hv.w, wv.w, acc[3][3]);
    }

    #pragma unroll
    for (int i = 0; i < 4; ++i) {
        if (nb + n0 + i < Nn) {
            __half2 lo = __floats2half2_rn(acc[i][0], acc[i][1]);
            __half2 hi = __floats2half2_rn(acc[i][2], acc[i][3]);
            uint2 pack;
            pack.x = *(const unsigned int*)&lo;
            pack.y = *(const unsigned int*)&hi;
            *(uint2*)&t[((size_t)w * Nn + nb + n0 + i) * 64 + oc0] = pack;
        }
    }
}

// ---------------------------------------------------------------------------
// Counting-sort-by-dst preamble (unchanged).
// ---------------------------------------------------------------------------
__global__ __launch_bounds__(256) void hist_kernel(
    const int* __restrict__ ei, int* __restrict__ deg)
{
    const int w = blockIdx.y;
    const int e = blockIdx.x * 256 + threadIdx.x;
    const int dst = ei[(size_t)w * 2 * En + En + e];
    atomicAdd(&deg[w * Nn + dst], 1);
}

__global__ __launch_bounds__(64) void scan_kernel(
    const int* __restrict__ deg, int* __restrict__ offs, int* __restrict__ curs)
{
    const int w = blockIdx.x;
    const int lane = threadIdx.x;
    int running = 0;
    for (int base = 0; base < Nn; base += 64) {
        const int i = base + lane;
        int v = (i < Nn) ? deg[w * Nn + i] : 0;
        int sum = v;
        #pragma unroll
        for (int d = 1; d < 64; d <<= 1) {
            int t = __shfl_up(sum, d);
            if (lane >= d) sum += t;
        }
        const int excl = sum - v;
        if (i < Nn) {
            offs[w * OFFS_STRIDE + i] = running + excl;
            curs[w * Nn + i]          = running + excl;
        }
        running += __shfl(sum, 63);
    }
    if (lane == 0) offs[w * OFFS_STRIDE + Nn] = running;
}

__global__ __launch_bounds__(256) void sortpairs_kernel(
    const int* __restrict__ ei, const float* __restrict__ ew,
    int* __restrict__ curs, float2* __restrict__ pairs)
{
    const int w = blockIdx.y;
    const int e = blockIdx.x * 256 + threadIdx.x;
    const int* eis = ei + (size_t)w * 2 * En;
    const int src = eis[e];
    const int dst = eis[En + e];
    const float wt = ew[(size_t)w * En + e];
    const int pos = atomicAdd(&curs[w * Nn + dst], 1);
    pairs[(size_t)w * En + pos] = make_float2(__int_as_float(src), wt);
}

// ---------------------------------------------------------------------------
// Atomic-free aggregation: one wave per dst node, lane = channel.
// t is fp16 -> gather traffic halved (128 B/edge).
// ---------------------------------------------------------------------------
template<bool LAST>
__global__ __launch_bounds__(256) void agg_kernel(
    const __half* __restrict__ t, const float2* __restrict__ pairs,
    const int* __restrict__ offs, const float* __restrict__ b,
    const float* __restrict__ x, float* __restrict__ out)
{
    const int w    = blockIdx.y;
    const int d    = blockIdx.x * 4 + (threadIdx.x >> 6);
    const int lane = threadIdx.x & 63;
    const int* ow  = offs + w * OFFS_STRIDE;
    const int beg = ow[d];
    const int end = ow[d + 1];
    const float2* pw = pairs + (size_t)w * En;
    const __half* tw = t + (size_t)w * Nn * Cn;

    float acc = 0.f;
    int i = beg;
    for (; i + 2 <= end; i += 2) {
        float2 p0 = pw[i];
        float2 p1 = pw[i + 1];
        const float v0 = __half2float(tw[(size_t)__float_as_int(p0.x) * Cn + lane]);
        const float v1 = __half2float(tw[(size_t)__float_as_int(p1.x) * Cn + lane]);
        acc = fmaf(p0.y, v0, acc);
        acc = fmaf(p1.y, v1, acc);
    }
    if (i < end) {
        float2 p0 = pw[i];
        acc = fmaf(p0.y, __half2float(tw[(size_t)__float_as_int(p0.x) * Cn + lane]), acc);
    }

    float v = elu_f(acc + b[w * Cn + lane]);
    const size_t oi = ((size_t)w * Nn + d) * Cn + lane;
    if (LAST) v += x[oi];
    out[oi] = v;
}

// ---------------------------------------------------------------------------
// ws layout (floats):
//   [0)          pairs : 7,680,000
//   [7,680,000)  offs  :   240,384 (int)
//   [7,920,384)  curs  :   240,000 (int)
//   [8,160,384)  deg   :   240,000 (int)  -- reused as wT after scan
//   [8,400,384)  H     : 15,360,000
// t (fp16, WNC halfs) lives in d_out between matmul and agg; final result is
// built in H then copied to d_out.
// ---------------------------------------------------------------------------
extern "C" void kernel_launch(void* const* d_in, const int* in_sizes, int n_in,
                              void* d_out, int out_size, void* d_ws, size_t ws_size,
                              hipStream_t stream)
{
    const float* x    = (const float*)d_in[0];
    const int*   ei   = (const int*)d_in[1];
    const float* ew   = (const float*)d_in[2];
    const float* sw1  = (const float*)d_in[3];
    const float* sb1  = (const float*)d_in[4];
    const float* gw1  = (const float*)d_in[5];
    const float* gb1  = (const float*)d_in[6];
    const float* sw3  = (const float*)d_in[7];
    const float* sb3  = (const float*)d_in[8];
    const float* gw3  = (const float*)d_in[9];
    const float* gb3  = (const float*)d_in[10];
    const float* sw5  = (const float*)d_in[11];
    const float* sb5  = (const float*)d_in[12];
    const float* gw5  = (const float*)d_in[13];
    const float* gb5  = (const float*)d_in[14];
    const float* sw7  = (const float*)d_in[15];
    const float* sb7  = (const float*)d_in[16];
    const float* gw7  = (const float*)d_in[17];
    const float* gb7  = (const float*)d_in[18];
    const float* gcnw = (const float*)d_in[19];
    const float* gcnb = (const float*)d_in[20];
    float* out = (float*)d_out;
    __half* Th = (__half*)d_out;

    const size_t WNC = (size_t)Wn * Nn * Cn;
    const int mm_grid = (Nn + 63) / 64;    // 313 — tail block guarded

    float2* pairs = (float2*)d_ws;
    int*    offs  = (int*)((float*)d_ws + 7680000);
    int*    curs  = offs + 240384;
    int*    deg   = curs + 240000;
    float*  wT    = (float*)deg;          // reused after scan_kernel
    float*  H     = (float*)(deg + 240000);

    // --- sort preamble ---
    hipMemsetAsync(deg, 0, (size_t)Wn * Nn * sizeof(int), stream);
    hist_kernel<<<dim3(En / 256, Wn), 256, 0, stream>>>(ei, deg);
    scan_kernel<<<Wn, 64, 0, stream>>>(deg, offs, curs);          // last read of deg
    sortpairs_kernel<<<dim3(En / 256, Wn), 256, 0, stream>>>(ei, ew, curs, pairs);

    // --- weight transpose into the dead deg region ---
    transw_kernel<<<8, 256, 0, stream>>>(sw1, gw1, wT + 0,     1);
    transw_kernel<<<8, 256, 0, stream>>>(sw3, gw3, wT + 2048,  3);
    transw_kernel<<<8, 256, 0, stream>>>(sw5, gw5, wT + 8192,  5);
    transw_kernel<<<8, 256, 0, stream>>>(sw7, gw7, wT + 18432, 7);

    // --- feature path ---
    inception_kernel<<<dim3(Nn / 16, 4), 256, 0, stream>>>(
        x, sb1, gb1, sb3, gb3, sb5, gb5, sb7, gb7, wT, H);

    // hop 0
    matmul_half_kernel<<<dim3(mm_grid, Wn), 256, 0, stream>>>(H, gcnw, Th);
    agg_kernel<false><<<dim3(Nn / 4, Wn), 256, 0, stream>>>(
        Th, pairs, offs, gcnb, nullptr, H);

    // hop 1
    matmul_half_kernel<<<dim3(mm_grid, Wn), 256, 0, stream>>>(
        H, gcnw + (size_t)Wn * Cn * Cn, Th);
    agg_kernel<true><<<dim3(Nn / 4, Wn), 256, 0, stream>>>(
        Th, pairs, offs, gcnb + (size_t)Wn * Cn, x, H);
    hipMemcpyAsync(out, H, WNC * sizeof(float), hipMemcpyDeviceToDevice, stream);
}

// Round 6
// 1188.652 us; speedup vs baseline: 1.4801x; 1.4801x over previous
//
#include <hip/hip_runtime.h>
#include <hip/hip_fp16.h>
#include <cstddef>

#define Wn 12
#define Nn 20000
#define Cn 64
#define En 320000
#define OFFS_STRIDE 20032

typedef _Float16 h2v __attribute__((ext_vector_type(2)));
typedef _Float16 h4v __attribute__((ext_vector_type(4)));

__device__ __forceinline__ float elu_f(float v) {
    return v > 0.f ? v : (expf(v) - 1.f);
}

// fp16 pair dot with fp32 accumulate. v_dot2_f32_f16 where available.
__device__ __forceinline__ float fdot2f(h2v a, h2v b, float c) {
#if __has_builtin(__builtin_amdgcn_fdot2)
    return __builtin_amdgcn_fdot2(a, b, c, false);
#else
    return fmaf((float)a.x, (float)b.x, fmaf((float)a.y, (float)b.y, c));
#endif
}

// ---------------------------------------------------------------------------
// Weight transpose + fp16 cast: [oc][ic][t] -> [oc][t][ic] halfs.
// ---------------------------------------------------------------------------
__global__ __launch_bounds__(256) void transw_kernel(
    const float* __restrict__ swv, const float* __restrict__ gwv,
    __half* __restrict__ dst, int K)
{
    const int tot = 16 * 64 * K;
    for (int i = threadIdx.x + blockIdx.x * 256; i < 2 * tot; i += gridDim.x * 256) {
        const float* srcp = (i < tot) ? swv : gwv;
        int j  = (i < tot) ? i : i - tot;
        int oc = j / (64 * K);
        int r  = j - oc * 64 * K;     // t*64 + ic
        int t  = r >> 6;
        int ic = r & 63;
        dst[i] = __float2half(srcp[(oc * 64 + ic) * K + t]);
    }
}

// ---------------------------------------------------------------------------
// Inception gated temporal conv. K-group per blockIdx.y (uniform waves),
// x staged as fp16 in 27.6 KB LDS (node stride 432 h2 -> 2-way alias, free),
// dot2 inner loop (2 MACs/instr). __launch_bounds__(256,4) caps VGPR at 128
// -> 4 blocks/CU (round 5: 62 KB LDS + VGPR 132 = 11% occupancy, VALU 39%).
// ---------------------------------------------------------------------------
template<int K>
__device__ __forceinline__ void incep_core(
    const h2v* __restrict__ xq,      // node base; row stride 36 h2, chunk j at +4
    const h2v* __restrict__ swT,     // + ocl*K*32 applied
    const h2v* __restrict__ gwT,
    float* accs, float* accg)
{
    constexpr int P = (K - 1) / 2;
    for (int j = 0; j < 8; ++j) {            // 8 chunks of 8 input channels
        h2v xr[Wn][4];
        #pragma unroll
        for (int w = 0; w < Wn; ++w) {
            const float4 raw = *(const float4*)&xq[w * 36 + j * 4];
            xr[w][0] = __builtin_bit_cast(h2v, raw.x);
            xr[w][1] = __builtin_bit_cast(h2v, raw.y);
            xr[w][2] = __builtin_bit_cast(h2v, raw.z);
            xr[w][3] = __builtin_bit_cast(h2v, raw.w);
        }
        #pragma unroll
        for (int t = 0; t < K; ++t) {
            const float4 rs = *(const float4*)&swT[t * 32 + j * 4];
            const float4 rg = *(const float4*)&gwT[t * 32 + j * 4];
            h2v ws[4], wg[4];
            ws[0] = __builtin_bit_cast(h2v, rs.x);
            ws[1] = __builtin_bit_cast(h2v, rs.y);
            ws[2] = __builtin_bit_cast(h2v, rs.z);
            ws[3] = __builtin_bit_cast(h2v, rs.w);
            wg[0] = __builtin_bit_cast(h2v, rg.x);
            wg[1] = __builtin_bit_cast(h2v, rg.y);
            wg[2] = __builtin_bit_cast(h2v, rg.z);
            wg[3] = __builtin_bit_cast(h2v, rg.w);
            #pragma unroll
            for (int w = 0; w < Wn; ++w) {
                const int wp = w + t - P;
                if (wp >= 0 && wp < Wn) {
                    accs[w] = fdot2f(xr[wp][0], ws[0], accs[w]);
                    accs[w] = fdot2f(xr[wp][1], ws[1], accs[w]);
                    accs[w] = fdot2f(xr[wp][2], ws[2], accs[w]);
                    accs[w] = fdot2f(xr[wp][3], ws[3], accs[w]);
                    accg[w] = fdot2f(xr[wp][0], wg[0], accg[w]);
                    accg[w] = fdot2f(xr[wp][1], wg[1], accg[w]);
                    accg[w] = fdot2f(xr[wp][2], wg[2], accg[w]);
                    accg[w] = fdot2f(xr[wp][3], wg[3], accg[w]);
                }
            }
        }
    }
}

__global__ __launch_bounds__(256, 4) void inception_kernel(
    const float* __restrict__ x,
    const float* __restrict__ sb1, const float* __restrict__ gb1,
    const float* __restrict__ sb3, const float* __restrict__ gb3,
    const float* __restrict__ sb5, const float* __restrict__ gb5,
    const float* __restrict__ sb7, const float* __restrict__ gb7,
    const __half* __restrict__ wT,
    float* __restrict__ h)
{
    __shared__ h2v xsh[16 * 432];            // 27,648 B
    const int tid = threadIdx.x;
    const int nb  = blockIdx.x * 16;
    const int grp = blockIdx.y;              // K-group 0..3

    const float4* xg = (const float4*)x;
    for (int idx = tid; idx < 3072; idx += 256) {
        int nl  = idx / 192;
        int rem = idx - nl * 192;
        int w  = rem >> 4;
        int c4 = rem & 15;
        float4 v = xg[((size_t)w * Nn + nb + nl) * 16 + c4];
        h4v p = { (_Float16)v.x, (_Float16)v.y, (_Float16)v.z, (_Float16)v.w };
        *(h4v*)&xsh[nl * 432 + w * 36 + c4 * 2] = p;
    }
    __syncthreads();

    const int lane = tid & 63;
    const int ocl  = lane & 15;
    const int node = (tid >> 6) * 4 + (lane >> 4);
    const h2v* xq  = xsh + node * 432;
    const h2v* wT2 = (const h2v*)wT;

    float bs, bg;
    switch (grp) {
      case 0:  bs = sb1[ocl]; bg = gb1[ocl]; break;
      case 1:  bs = sb3[ocl]; bg = gb3[ocl]; break;
      case 2:  bs = sb5[ocl]; bg = gb5[ocl]; break;
      default: bs = sb7[ocl]; bg = gb7[ocl]; break;
    }
    float accs[Wn], accg[Wn];
    #pragma unroll
    for (int w = 0; w < Wn; ++w) { accs[w] = bs; accg[w] = bg; }

    // h2-unit bases: sig {0,1024,4096,9216}, gate {512,2560,6656,12800}
    switch (grp) {
      case 0:  incep_core<1>(xq, wT2 + 0    + ocl * 32,  wT2 + 512   + ocl * 32,  accs, accg); break;
      case 1:  incep_core<3>(xq, wT2 + 1024 + ocl * 96,  wT2 + 2560  + ocl * 96,  accs, accg); break;
      case 2:  incep_core<5>(xq, wT2 + 4096 + ocl * 160, wT2 + 6656  + ocl * 160, accs, accg); break;
      default: incep_core<7>(xq, wT2 + 9216 + ocl * 224, wT2 + 12800 + ocl * 224, accs, accg); break;
    }

    const int n  = nb + node;
    const int oc = grp * 16 + ocl;
    #pragma unroll
    for (int w = 0; w < Wn; ++w) {
        float s = accs[w];
        float g = accg[w];
        float r  = s > 0.f ? s : 0.f;
        float sg = 1.f / (1.f + expf(-g));
        h[((size_t)w * Nn + n) * Cn + oc] = r * sg;
    }
}

// ---------------------------------------------------------------------------
// Per-window (N x 64) @ (64 x 64) matmul, fp32 in -> fp16 out. Tail guarded.
// ---------------------------------------------------------------------------
__global__ __launch_bounds__(256) void matmul_half_kernel(
    const float* __restrict__ h, const float* __restrict__ gw,
    __half* __restrict__ t)
{
    const int w  = blockIdx.y;
    const int nb = blockIdx.x * 64;
    __shared__ float wm[64 * 64];
    __shared__ float hT[64 * 64];
    const int tid = threadIdx.x;

    const float4* wsrc = (const float4*)(gw + (size_t)w * 4096);
    float4* wm4 = (float4*)wm;
    for (int i = tid; i < 1024; i += 256) wm4[i] = wsrc[i];

    {
        const int n = tid >> 2, icq = tid & 3;
        const int nclamp = (nb + n < Nn) ? (nb + n) : (Nn - 1);
        const float4* hsrc = (const float4*)(h + ((size_t)w * Nn + nclamp) * 64);
        #pragma unroll
        for (int k = 0; k < 4; ++k) {
            float4 v = hsrc[icq + 4 * k];
            int ic = (icq + 4 * k) * 4;
            hT[(ic + 0) * 64 + n] = v.x;
            hT[(ic + 1) * 64 + n] = v.y;
            hT[(ic + 2) * 64 + n] = v.z;
            hT[(ic + 3) * 64 + n] = v.w;
        }
    }
    __syncthreads();

    const int oc0 = (tid & 15) * 4;
    const int n0  = (tid >> 4) * 4;
    float acc[4][4] = {{0.f}};
    #pragma unroll
    for (int ic = 0; ic < 64; ++ic) {
        const float4 hv = *(const float4*)&hT[ic * 64 + n0];
        const float4 wv = *(const float4*)&wm[ic * 64 + oc0];
        acc[0][0] = fmaf(hv.x, wv.x, acc[0][0]);
        acc[0][1] = fmaf(hv.x, wv.y, acc[0][1]);
        acc[0][2] = fmaf(hv.x, wv.z, acc[0][2]);
        acc[0][3] = fmaf(hv.x, wv.w, acc[0][3]);
        acc[1][0] = fmaf(hv.y, wv.x, acc[1][0]);
        acc[1][1] = fmaf(hv.y, wv.y, acc[1][1]);
        acc[1][2] = fmaf(hv.y, wv.z, acc[1][2]);
        acc[1][3] = fmaf(hv.y, wv.w, acc[1][3]);
        acc[2][0] = fmaf(hv.z, wv.x, acc[2][0]);
        acc[2][1] = fmaf(hv.z, wv.y, acc[2][1]);
        acc[2][2] = fmaf(hv.z, wv.z, acc[2][2]);
        acc[2][3] = fmaf(hv.z, wv.w, acc[2][3]);
        acc[3][0] = fmaf(hv.w, wv.x, acc[3][0]);
        acc[3][1] = fmaf(hv.w, wv.y, acc[3][1]);
        acc[3][2] = fmaf(hv.w, wv.z, acc[3][2]);
        acc[3][3] = fmaf(hv.w, wv.w, acc[3][3]);
    }

    #pragma unroll
    for (int i = 0; i < 4; ++i) {
        if (nb + n0 + i < Nn) {
            __half2 lo = __floats2half2_rn(acc[i][0], acc[i][1]);
            __half2 hi = __floats2half2_rn(acc[i][2], acc[i][3]);
            uint2 pack;
            pack.x = *(const unsigned int*)&lo;
            pack.y = *(const unsigned int*)&hi;
            *(uint2*)&t[((size_t)w * Nn + nb + n0 + i) * 64 + oc0] = pack;
        }
    }
}

// ---------------------------------------------------------------------------
// Counting-sort preamble.
// ---------------------------------------------------------------------------
__global__ __launch_bounds__(256) void hist_kernel(
    const int* __restrict__ ei, int* __restrict__ deg)
{
    const int w = blockIdx.y;
    const int e = blockIdx.x * 256 + threadIdx.x;
    const int dst = ei[(size_t)w * 2 * En + En + e];
    atomicAdd(&deg[w * Nn + dst], 1);
}

// 12 blocks x 1024 threads: hierarchical scan (was 12 waves on the whole GPU).
__global__ __launch_bounds__(1024) void scan_kernel(
    const int* __restrict__ deg, int* __restrict__ offs, int* __restrict__ curs)
{
    const int w   = blockIdx.x;
    const int tid = threadIdx.x;
    const int lane = tid & 63;
    const int wv   = tid >> 6;            // 0..15
    __shared__ int wsum[16];
    __shared__ int ctot;
    int running = 0;
    for (int base = 0; base < Nn; base += 1024) {
        const int i = base + tid;
        int v = (i < Nn) ? deg[w * Nn + i] : 0;
        int sum = v;
        #pragma unroll
        for (int d = 1; d < 64; d <<= 1) {
            int t = __shfl_up(sum, d);
            if (lane >= d) sum += t;
        }
        if (lane == 63) wsum[wv] = sum;
        __syncthreads();
        if (tid < 16) {
            int orig = wsum[tid];
            int s = orig;
            #pragma unroll
            for (int d = 1; d < 16; d <<= 1) {
                int t = __shfl_up(s, d);
                if (tid >= d) s += t;
            }
            wsum[tid] = s - orig;         // exclusive across waves
            if (tid == 15) ctot = s;
        }
        __syncthreads();
        if (i < Nn) {
            const int e = running + wsum[wv] + (sum - v);
            offs[w * OFFS_STRIDE + i] = e;
            curs[w * Nn + i] = e;
        }
        running += ctot;
        __syncthreads();
    }
    if (tid == 0) offs[w * OFFS_STRIDE + Nn] = running;
}

// XCD-affinity swizzle: all blocks of window w share b%8 (1D grid, 15000).
__global__ __launch_bounds__(256) void sortpairs_kernel(
    const int* __restrict__ ei, const float* __restrict__ ew,
    int* __restrict__ curs, float2* __restrict__ pairs)
{
    const int b = blockIdx.x;
    const int r = b & 7, q = b >> 3;
    int w, eg;
    if (q < 1250) { w = r; eg = q; }
    else { int q2 = q - 1250; w = 8 + (r >> 1); eg = q2 * 2 + (r & 1); }
    const int e = eg * 256 + threadIdx.x;
    const int* eis = ei + (size_t)w * 2 * En;
    const int src = eis[e];
    const int dst = eis[En + e];
    const float wt = ew[(size_t)w * En + e];
    const int pos = atomicAdd(&curs[w * Nn + dst], 1);
    pairs[(size_t)w * En + pos] = make_float2(__int_as_float(src), wt);
}

// ---------------------------------------------------------------------------
// Aggregation: one wave per dst; 2 edges in flight (32 lanes x __half2 each,
// 128 B/edge in half the instructions). XCD-affinity swizzle: blocks of
// window w land on b%8=f(w) -> each XCD's L2 holds <=2 t-slabs (5 MB) instead
// of all 12 (31 MB thrash).
// ---------------------------------------------------------------------------
template<bool LAST>
__global__ __launch_bounds__(256) void agg_kernel(
    const __half* __restrict__ t, const float2* __restrict__ pairs,
    const int* __restrict__ offs, const float* __restrict__ b,
    const float* __restrict__ x, float* __restrict__ out)
{
    const int blk = blockIdx.x;
    const int r = blk & 7, q = blk >> 3;
    int w, ng;
    if (q < 5000) { w = r; ng = q; }
    else { int q2 = q - 5000; w = 8 + (r >> 1); ng = q2 * 2 + (r & 1); }

    const int d    = ng * 4 + (threadIdx.x >> 6);
    const int lane = threadIdx.x & 63;
    const int hgrp = lane >> 5;           // which of 2 concurrent edges
    const int c    = lane & 31;           // channel pair index
    const int* ow  = offs + w * OFFS_STRIDE;
    const int beg = ow[d];
    const int end = ow[d + 1];
    const float2* pw = pairs + (size_t)w * En;
    const __half* tw = t + (size_t)w * Nn * Cn;

    float ax = 0.f, ay = 0.f;
    int i = beg;
    for (; i + 4 <= end; i += 4) {
        float2 p0 = pw[i + hgrp];
        float2 p1 = pw[i + 2 + hgrp];
        float2 f0 = __half22float2(*(const __half2*)&tw[(size_t)__float_as_int(p0.x) * Cn + 2 * c]);
        float2 f1 = __half22float2(*(const __half2*)&tw[(size_t)__float_as_int(p1.x) * Cn + 2 * c]);
        ax = fmaf(p0.y, f0.x, ax);
        ay = fmaf(p0.y, f0.y, ay);
        ax = fmaf(p1.y, f1.x, ax);
        ay = fmaf(p1.y, f1.y, ay);
    }
    if (i + 2 <= end) {
        float2 p0 = pw[i + hgrp];
        float2 f0 = __half22float2(*(const __half2*)&tw[(size_t)__float_as_int(p0.x) * Cn + 2 * c]);
        ax = fmaf(p0.y, f0.x, ax);
        ay = fmaf(p0.y, f0.y, ay);
        i += 2;
    }
    if (i < end && hgrp == 0) {
        float2 p0 = pw[i];
        float2 f0 = __half22float2(*(const __half2*)&tw[(size_t)__float_as_int(p0.x) * Cn + 2 * c]);
        ax = fmaf(p0.y, f0.x, ax);
        ay = fmaf(p0.y, f0.y, ay);
    }

    ax += __shfl_xor(ax, 32);
    ay += __shfl_xor(ay, 32);

    if (hgrp == 0) {
        const float2 bv = *(const float2*)&b[w * Cn + 2 * c];
        float vx = elu_f(ax + bv.x);
        float vy = elu_f(ay + bv.y);
        const size_t oi = ((size_t)w * Nn + d) * Cn + 2 * c;
        if (LAST) {
            const float2 xv = *(const float2*)&x[oi];
            vx += xv.x;
            vy += xv.y;
        }
        *(float2*)&out[oi] = make_float2(vx, vy);
    }
}

// ---------------------------------------------------------------------------
// ws layout (floats):
//   [0)          pairs : 7,680,000
//   [7,680,000)  offs  :   240,384 (int)
//   [7,920,384)  curs  :   240,000 (int)
//   [8,160,384)  deg   :   240,000 (int)  -- reused as wT (32768 halfs) after scan
//   [8,400,384)  H     : 15,360,000
// t (fp16) lives in d_out between matmul and agg; final result built in H,
// then copied to d_out.
// ---------------------------------------------------------------------------
extern "C" void kernel_launch(void* const* d_in, const int* in_sizes, int n_in,
                              void* d_out, int out_size, void* d_ws, size_t ws_size,
                              hipStream_t stream)
{
    const float* x    = (const float*)d_in[0];
    const int*   ei   = (const int*)d_in[1];
    const float* ew   = (const float*)d_in[2];
    const float* sw1  = (const float*)d_in[3];
    const float* sb1  = (const float*)d_in[4];
    const float* gw1  = (const float*)d_in[5];
    const float* gb1  = (const float*)d_in[6];
    const float* sw3  = (const float*)d_in[7];
    const float* sb3  = (const float*)d_in[8];
    const float* gw3  = (const float*)d_in[9];
    const float* gb3  = (const float*)d_in[10];
    const float* sw5  = (const float*)d_in[11];
    const float* sb5  = (const float*)d_in[12];
    const float* gw5  = (const float*)d_in[13];
    const float* gb5  = (const float*)d_in[14];
    const float* sw7  = (const float*)d_in[15];
    const float* sb7  = (const float*)d_in[16];
    const float* gw7  = (const float*)d_in[17];
    const float* gb7  = (const float*)d_in[18];
    const float* gcnw = (const float*)d_in[19];
    const float* gcnb = (const float*)d_in[20];
    float* out = (float*)d_out;
    __half* Th = (__half*)d_out;

    const size_t WNC = (size_t)Wn * Nn * Cn;
    const int mm_grid = (Nn + 63) / 64;    // 313 — tail block guarded

    float2* pairs = (float2*)d_ws;
    int*    offs  = (int*)((float*)d_ws + 7680000);
    int*    curs  = offs + 240384;
    int*    deg   = curs + 240000;
    __half* wT    = (__half*)deg;          // reused after scan_kernel
    float*  H     = (float*)(deg + 240000);

    // --- sort preamble ---
    hipMemsetAsync(deg, 0, (size_t)Wn * Nn * sizeof(int), stream);
    hist_kernel<<<dim3(En / 256, Wn), 256, 0, stream>>>(ei, deg);
    scan_kernel<<<Wn, 1024, 0, stream>>>(deg, offs, curs);        // last read of deg
    sortpairs_kernel<<<15000, 256, 0, stream>>>(ei, ew, curs, pairs);

    // --- weight transpose (fp16) into the dead deg region ---
    transw_kernel<<<8, 256, 0, stream>>>(sw1, gw1, wT + 0,     1);
    transw_kernel<<<8, 256, 0, stream>>>(sw3, gw3, wT + 2048,  3);
    transw_kernel<<<8, 256, 0, stream>>>(sw5, gw5, wT + 8192,  5);
    transw_kernel<<<8, 256, 0, stream>>>(sw7, gw7, wT + 18432, 7);

    // --- feature path ---
    inception_kernel<<<dim3(Nn / 16, 4), 256, 0, stream>>>(
        x, sb1, gb1, sb3, gb3, sb5, gb5, sb7, gb7, wT, H);

    // hop 0
    matmul_half_kernel<<<dim3(mm_grid, Wn), 256, 0, stream>>>(H, gcnw, Th);
    agg_kernel<false><<<60000, 256, 0, stream>>>(
        Th, pairs, offs, gcnb, nullptr, H);

    // hop 1
    matmul_half_kernel<<<dim3(mm_grid, Wn), 256, 0, stream>>>(
        H, gcnw + (size_t)Wn * Cn * Cn, Th);
    agg_kernel<true><<<60000, 256, 0, stream>>>(
        Th, pairs, offs, gcnb + (size_t)Wn * Cn, x, H);
    hipMemcpyAsync(out, H, WNC * sizeof(float), hipMemcpyDeviceToDevice, stream);
}